// Round 1
// baseline (1960.707 us; speedup 1.0000x reference)
//
#include <hip/hip_runtime.h>
#include <math.h>

#define N_NODES 100000
#define N_EDGES 3200000
#define F_IN 128
#define HID 16
#define C_OUT 10

// ---------------- degree / normalization ----------------

__global__ void k_init_deg(float* __restrict__ deg) {
    int i = blockIdx.x * blockDim.x + threadIdx.x;
    if (i < N_NODES) deg[i] = 1.0f;   // self-loop
}

__global__ void k_count(const int* __restrict__ col, float* __restrict__ deg) {
    int e = blockIdx.x * blockDim.x + threadIdx.x;
    if (e < N_EDGES) atomicAdd(&deg[col[e]], 1.0f);
}

__global__ void k_rsqrt(float* __restrict__ deg) {
    int i = blockIdx.x * blockDim.x + threadIdx.x;
    if (i < N_NODES) deg[i] = rsqrtf(deg[i]);   // deg buffer becomes dis
}

// ---------------- layer 1: h1 = x @ W1 ; agg1 = h1 * dis^2 (self loop) ----------------

__global__ void k_gemm1(const float* __restrict__ x, const float* __restrict__ W1,
                        const float* __restrict__ dis,
                        float* __restrict__ h1, float* __restrict__ agg1) {
    __shared__ float Ws[F_IN * HID];  // 8 KB
    for (int t = threadIdx.x; t < F_IN * HID; t += blockDim.x) Ws[t] = W1[t];
    __syncthreads();

    int row = blockIdx.x * blockDim.x + threadIdx.x;
    if (row >= N_NODES) return;

    float acc[HID];
#pragma unroll
    for (int j = 0; j < HID; j++) acc[j] = 0.f;

    const float4* xr = (const float4*)(x + (size_t)row * F_IN);
#pragma unroll 4
    for (int k4 = 0; k4 < F_IN / 4; k4++) {
        float4 v = xr[k4];
        int k = k4 * 4;
#pragma unroll
        for (int j = 0; j < HID; j++) {
            // all lanes read same LDS address -> broadcast, conflict-free
            acc[j] += v.x * Ws[(k + 0) * HID + j];
            acc[j] += v.y * Ws[(k + 1) * HID + j];
            acc[j] += v.z * Ws[(k + 2) * HID + j];
            acc[j] += v.w * Ws[(k + 3) * HID + j];
        }
    }

    float d = dis[row];
    float d2 = d * d;
    float* h1r = h1 + (size_t)row * HID;
    float* a1r = agg1 + (size_t)row * HID;
#pragma unroll
    for (int j4 = 0; j4 < HID / 4; j4++) {
        float4 hv = make_float4(acc[j4 * 4 + 0], acc[j4 * 4 + 1], acc[j4 * 4 + 2], acc[j4 * 4 + 3]);
        ((float4*)h1r)[j4] = hv;
        float4 av = make_float4(hv.x * d2, hv.y * d2, hv.z * d2, hv.w * d2);
        ((float4*)a1r)[j4] = av;
    }
}

// ---------------- scatter layer 1: agg1[c] += h1[r] * dis[r]*dis[c] ----------------
// 4 threads per edge; each handles 4 of the 16 features (one float4 = 16B per lane,
// the 4 lanes of an edge together fetch one contiguous 64B h1 row).

__global__ void k_scatter1(const int* __restrict__ row, const int* __restrict__ col,
                           const float* __restrict__ dis, const float* __restrict__ h1,
                           float* __restrict__ agg1) {
    long long t = (long long)blockIdx.x * blockDim.x + threadIdx.x;
    if (t >= (long long)N_EDGES * 4) return;
    int e = (int)(t >> 2);
    int q = (int)(t & 3);
    int r = row[e];
    int c = col[e];
    float w = dis[r] * dis[c];
    float4 v = *(const float4*)(h1 + (size_t)r * HID + q * 4);
    float* dst = agg1 + (size_t)c * HID + q * 4;
    atomicAdd(dst + 0, v.x * w);
    atomicAdd(dst + 1, v.y * w);
    atomicAdd(dst + 2, v.z * w);
    atomicAdd(dst + 3, v.w * w);
}

// ---------------- layer 2: h = relu(agg1 + b1); h2 = h @ W2 ; agg2 = h2 * dis^2 ----------------

__global__ void k_layer2(const float* __restrict__ agg1, const float* __restrict__ b1,
                         const float* __restrict__ W2, const float* __restrict__ dis,
                         float* __restrict__ h2, float* __restrict__ agg2) {
    __shared__ float Ws[HID * C_OUT];  // 160 floats
    __shared__ float b1s[HID];
    if (threadIdx.x < HID * C_OUT) Ws[threadIdx.x] = W2[threadIdx.x];
    if (threadIdx.x < HID) b1s[threadIdx.x] = b1[threadIdx.x];
    __syncthreads();

    int i = blockIdx.x * blockDim.x + threadIdx.x;
    if (i >= N_NODES) return;

    float acc[C_OUT];
#pragma unroll
    for (int k = 0; k < C_OUT; k++) acc[k] = 0.f;

    const float4* ar = (const float4*)(agg1 + (size_t)i * HID);
#pragma unroll
    for (int j4 = 0; j4 < HID / 4; j4++) {
        float4 v = ar[j4];
        float vv[4] = {v.x, v.y, v.z, v.w};
#pragma unroll
        for (int u = 0; u < 4; u++) {
            int j = j4 * 4 + u;
            float h = fmaxf(vv[u] + b1s[j], 0.f);
#pragma unroll
            for (int k = 0; k < C_OUT; k++) acc[k] += h * Ws[j * C_OUT + k];
        }
    }

    float d = dis[i];
    float d2 = d * d;
    float* h2r = h2 + (size_t)i * C_OUT;
    float* a2r = agg2 + (size_t)i * C_OUT;
#pragma unroll
    for (int k = 0; k < C_OUT; k++) {
        h2r[k] = acc[k];
        a2r[k] = acc[k] * d2;
    }
}

// ---------------- scatter layer 2: agg2[c] += h2[r] * dis[r]*dis[c] ----------------
// 2 threads per edge, 5 features each.

__global__ void k_scatter2(const int* __restrict__ row, const int* __restrict__ col,
                           const float* __restrict__ dis, const float* __restrict__ h2,
                           float* __restrict__ agg2) {
    long long t = (long long)blockIdx.x * blockDim.x + threadIdx.x;
    if (t >= (long long)N_EDGES * 2) return;
    int e = (int)(t >> 1);
    int q = (int)(t & 1);
    int r = row[e];
    int c = col[e];
    float w = dis[r] * dis[c];
    const float* src = h2 + (size_t)r * C_OUT + q * 5;
    float* dst = agg2 + (size_t)c * C_OUT + q * 5;
#pragma unroll
    for (int u = 0; u < 5; u++) atomicAdd(dst + u, src[u] * w);
}

// ---------------- final: logits = agg2 + b2 ; out = log_softmax(logits) ----------------

__global__ void k_final(const float* __restrict__ agg2, const float* __restrict__ b2,
                        float* __restrict__ out) {
    __shared__ float b2s[C_OUT];
    if (threadIdx.x < C_OUT) b2s[threadIdx.x] = b2[threadIdx.x];
    __syncthreads();

    int i = blockIdx.x * blockDim.x + threadIdx.x;
    if (i >= N_NODES) return;

    const float* ar = agg2 + (size_t)i * C_OUT;
    float v[C_OUT];
    float m = -1e30f;
#pragma unroll
    for (int k = 0; k < C_OUT; k++) {
        v[k] = ar[k] + b2s[k];
        m = fmaxf(m, v[k]);
    }
    float s = 0.f;
#pragma unroll
    for (int k = 0; k < C_OUT; k++) s += expf(v[k] - m);
    float ls = logf(s) + m;
    float* orow = out + (size_t)i * C_OUT;
#pragma unroll
    for (int k = 0; k < C_OUT; k++) orow[k] = v[k] - ls;
}

// ---------------- launch ----------------

extern "C" void kernel_launch(void* const* d_in, const int* in_sizes, int n_in,
                              void* d_out, int out_size, void* d_ws, size_t ws_size,
                              hipStream_t stream) {
    const float* x   = (const float*)d_in[0];
    const int*   ei  = (const int*)d_in[1];
    const float* W1  = (const float*)d_in[2];
    const float* b1  = (const float*)d_in[3];
    const float* W2  = (const float*)d_in[4];
    const float* b2  = (const float*)d_in[5];
    float* out = (float*)d_out;

    const int* row = ei;            // edge_index[0] = source
    const int* col = ei + N_EDGES;  // edge_index[1] = target

    // workspace layout (all 16B-aligned offsets)
    char* ws = (char*)d_ws;
    float* dis  = (float*)(ws);                                 // N floats      = 400000 B
    float* h1   = (float*)(ws + 400000);                        // N*16 floats   = 6400000 B
    float* agg1 = (float*)(ws + 400000 + 6400000);              // N*16 floats   = 6400000 B
    float* h2   = (float*)(ws + 400000 + 2 * 6400000);          // N*10 floats   = 4000000 B
    float* agg2 = (float*)(ws + 400000 + 2 * 6400000 + 4000000);// N*10 floats   = 4000000 B

    const int B = 256;
    int gN  = (N_NODES + B - 1) / B;
    int gE  = (N_EDGES + B - 1) / B;
    int gE4 = (int)(((long long)N_EDGES * 4 + B - 1) / B);
    int gE2 = (int)(((long long)N_EDGES * 2 + B - 1) / B);

    k_init_deg<<<gN, B, 0, stream>>>(dis);
    k_count  <<<gE, B, 0, stream>>>(col, dis);
    k_rsqrt  <<<gN, B, 0, stream>>>(dis);
    k_gemm1  <<<gN, B, 0, stream>>>(x, W1, dis, h1, agg1);
    k_scatter1<<<gE4, B, 0, stream>>>(row, col, dis, h1, agg1);
    k_layer2 <<<gN, B, 0, stream>>>(agg1, b1, W2, dis, h2, agg2);
    k_scatter2<<<gE2, B, 0, stream>>>(row, col, dis, h2, agg2);
    k_final  <<<gN, B, 0, stream>>>(agg2, b2, out);
}

// Round 3
// 757.247 us; speedup vs baseline: 2.5893x; 2.5893x over previous
//
#include <hip/hip_runtime.h>
#include <math.h>

#define N_NODES 100000
#define N_EDGES 3200000
#define F_IN 128
#define HID 16
#define C_OUT 10

typedef unsigned short u16;
typedef unsigned int u32;

__device__ __forceinline__ float bf2f(u16 u) {
    return __uint_as_float(((u32)u) << 16);
}
__device__ __forceinline__ u16 f2bf(float f) {
    u32 x = __float_as_uint(f);
    u32 r = (x + 0x7fffu + ((x >> 16) & 1u)) >> 16;  // round-nearest-even
    return (u16)r;
}

// ---------------- zero counters ----------------
__global__ void k_zero(int* __restrict__ deg, int* __restrict__ cursor) {
    int i = blockIdx.x * blockDim.x + threadIdx.x;
    if (i < N_NODES) { deg[i] = 0; cursor[i] = 0; }
}

// ---------------- in-degree count (int atomics) ----------------
__global__ void k_count(const int* __restrict__ col, int* __restrict__ deg) {
    int e = blockIdx.x * blockDim.x + threadIdx.x;
    if (e < N_EDGES) atomicAdd(&deg[col[e]], 1);
}

// ---------------- exclusive scan of degrees -> offs; dis = rsqrt(1+deg) ----------------
__global__ void k_scan(const int* __restrict__ deg, int* __restrict__ offs,
                       float* __restrict__ dis) {
    const int T = 1024;
    __shared__ int part[T];
    int t = threadIdx.x;
    const int chunk = (N_NODES + T - 1) / T;  // 98
    int base = t * chunk;
    int n = N_NODES - base; if (n < 0) n = 0; if (n > chunk) n = chunk;
    int s = 0;
    for (int i = 0; i < n; i++) s += deg[base + i];
    part[t] = s;
    __syncthreads();
    // Hillis-Steele inclusive scan (uniform control flow)
    for (int off = 1; off < T; off <<= 1) {
        int v = part[t];
        int u = (t >= off) ? part[t - off] : 0;
        __syncthreads();
        part[t] = v + u;
        __syncthreads();
    }
    int run = (t > 0) ? part[t - 1] : 0;  // exclusive prefix
    for (int i = 0; i < n; i++) {
        int d = deg[base + i];
        offs[base + i] = run;
        run += d;
        dis[base + i] = rsqrtf(1.0f + (float)d);
    }
    if (t == T - 1) offs[N_NODES] = part[T - 1];  // = E
}

// ---------------- bucket edges by target: csr_src[offs[c]..] = sources ----------------
__global__ void k_bucket(const int* __restrict__ row, const int* __restrict__ col,
                         const int* __restrict__ offs, int* __restrict__ cursor,
                         int* __restrict__ csr_src) {
    int e = blockIdx.x * blockDim.x + threadIdx.x;
    if (e >= N_EDGES) return;
    int c = col[e];
    int p = atomicAdd(&cursor[c], 1);
    csr_src[offs[c] + p] = row[e];
}

// ---------------- layer 1 GEMM: h1 = x @ W1  (bf16 out) ----------------
__global__ void k_gemm1(const float* __restrict__ x, const float* __restrict__ W1,
                        u16* __restrict__ h1) {
    __shared__ float Ws[F_IN * HID];  // 8 KB
    for (int t = threadIdx.x; t < F_IN * HID; t += blockDim.x) Ws[t] = W1[t];
    __syncthreads();

    int node = blockIdx.x * blockDim.x + threadIdx.x;
    if (node >= N_NODES) return;

    float acc[HID];
#pragma unroll
    for (int j = 0; j < HID; j++) acc[j] = 0.f;

    const float4* xr = (const float4*)(x + (size_t)node * F_IN);
#pragma unroll 2
    for (int k4 = 0; k4 < F_IN / 4; k4++) {
        float4 v = xr[k4];
        float xv[4] = {v.x, v.y, v.z, v.w};
#pragma unroll
        for (int kk = 0; kk < 4; kk++) {
            const float4* wr = (const float4*)(Ws + (k4 * 4 + kk) * HID);
            float4 w0 = wr[0], w1 = wr[1], w2 = wr[2], w3 = wr[3];  // b128 LDS reads
            float xs = xv[kk];
            acc[0]  += xs * w0.x; acc[1]  += xs * w0.y; acc[2]  += xs * w0.z; acc[3]  += xs * w0.w;
            acc[4]  += xs * w1.x; acc[5]  += xs * w1.y; acc[6]  += xs * w1.z; acc[7]  += xs * w1.w;
            acc[8]  += xs * w2.x; acc[9]  += xs * w2.y; acc[10] += xs * w2.z; acc[11] += xs * w2.w;
            acc[12] += xs * w3.x; acc[13] += xs * w3.y; acc[14] += xs * w3.z; acc[15] += xs * w3.w;
        }
    }

    u32 p[8];
#pragma unroll
    for (int i = 0; i < 8; i++)
        p[i] = (u32)f2bf(acc[2 * i]) | ((u32)f2bf(acc[2 * i + 1]) << 16);
    u32* dst = (u32*)(h1 + (size_t)node * HID);  // 32B row, 32B aligned
#pragma unroll
    for (int i = 0; i < 8; i++) dst[i] = p[i];
}

// ---------------- gather layer 1: agg1[c][f] = (h1[c][f]*dc + sum_s h1[s][f]*dis[s]) * dc ----------------
// 16 threads per node, one feature each; h1 reads coalesce to 32B per edge.
__global__ void k_gather1(const int* __restrict__ offs, const int* __restrict__ csr_src,
                          const float* __restrict__ dis, const u16* __restrict__ h1,
                          u16* __restrict__ agg1) {
    long long t = (long long)blockIdx.x * blockDim.x + threadIdx.x;
    if (t >= (long long)N_NODES * 16) return;
    int node = (int)(t >> 4);
    int f = (int)(t & 15);
    float dc = dis[node];
    int s0 = offs[node], s1 = offs[node + 1];
    float acc = bf2f(h1[(size_t)node * HID + f]) * dc;  // self loop (x dc again below)
    for (int j = s0; j < s1; j++) {
        int s = csr_src[j];               // same addr across the 16 lanes -> broadcast
        float w = dis[s];
        acc += bf2f(h1[(size_t)s * HID + f]) * w;
    }
    agg1[(size_t)node * HID + f] = f2bf(acc * dc);
}

// ---------------- layer 2: h = relu(agg1+b1); h2 = h @ W2 (bf16 out) ----------------
__global__ void k_layer2(const u16* __restrict__ agg1, const float* __restrict__ b1,
                         const float* __restrict__ W2, u16* __restrict__ h2) {
    __shared__ float Ws[HID * C_OUT];
    __shared__ float b1s[HID];
    if (threadIdx.x < HID * C_OUT) Ws[threadIdx.x] = W2[threadIdx.x];
    if (threadIdx.x < HID) b1s[threadIdx.x] = b1[threadIdx.x];
    __syncthreads();

    int node = blockIdx.x * blockDim.x + threadIdx.x;
    if (node >= N_NODES) return;

    const uint4* ar = (const uint4*)(agg1 + (size_t)node * HID);
    uint4 q0 = ar[0], q1 = ar[1];
    u32 qs[8] = {q0.x, q0.y, q0.z, q0.w, q1.x, q1.y, q1.z, q1.w};

    float acc[C_OUT];
#pragma unroll
    for (int k = 0; k < C_OUT; k++) acc[k] = 0.f;

#pragma unroll
    for (int i = 0; i < 8; i++) {
        u32 q = qs[i];
        float v0 = bf2f((u16)(q & 0xffff));
        float v1 = bf2f((u16)(q >> 16));
        int j0 = 2 * i, j1 = 2 * i + 1;
        float h0 = fmaxf(v0 + b1s[j0], 0.f);
        float h1v = fmaxf(v1 + b1s[j1], 0.f);
#pragma unroll
        for (int k = 0; k < C_OUT; k++) acc[k] += h0 * Ws[j0 * C_OUT + k] + h1v * Ws[j1 * C_OUT + k];
    }

    u32* dst = (u32*)(h2 + (size_t)node * C_OUT);  // 20B row, 4B aligned
#pragma unroll
    for (int i = 0; i < 5; i++)
        dst[i] = (u32)f2bf(acc[2 * i]) | ((u32)f2bf(acc[2 * i + 1]) << 16);
}

// ---------------- gather layer 2: agg2 -> d_out (fp32) ----------------
__global__ void k_gather2(const int* __restrict__ offs, const int* __restrict__ csr_src,
                          const float* __restrict__ dis, const u16* __restrict__ h2,
                          float* __restrict__ agg2) {
    long long t = (long long)blockIdx.x * blockDim.x + threadIdx.x;
    if (t >= (long long)N_NODES * 16) return;
    int node = (int)(t >> 4);
    int f = (int)(t & 15);
    if (f >= C_OUT) return;
    float dc = dis[node];
    int s0 = offs[node], s1 = offs[node + 1];
    float acc = bf2f(h2[(size_t)node * C_OUT + f]) * dc;
    for (int j = s0; j < s1; j++) {
        int s = csr_src[j];
        float w = dis[s];
        acc += bf2f(h2[(size_t)s * C_OUT + f]) * w;
    }
    agg2[(size_t)node * C_OUT + f] = acc * dc;
}

// ---------------- final: out = log_softmax(agg2 + b2), in place on d_out ----------------
__global__ void k_final(float* __restrict__ agg2, const float* __restrict__ b2) {
    __shared__ float b2s[C_OUT];
    if (threadIdx.x < C_OUT) b2s[threadIdx.x] = b2[threadIdx.x];
    __syncthreads();

    int i = blockIdx.x * blockDim.x + threadIdx.x;
    if (i >= N_NODES) return;

    float* ar = agg2 + (size_t)i * C_OUT;
    float v[C_OUT];
    float m = -1e30f;
#pragma unroll
    for (int k = 0; k < C_OUT; k++) {
        v[k] = ar[k] + b2s[k];
        m = fmaxf(m, v[k]);
    }
    float s = 0.f;
#pragma unroll
    for (int k = 0; k < C_OUT; k++) s += expf(v[k] - m);
    float ls = logf(s) + m;
#pragma unroll
    for (int k = 0; k < C_OUT; k++) ar[k] = v[k] - ls;
}

// ---------------- launch ----------------
extern "C" void kernel_launch(void* const* d_in, const int* in_sizes, int n_in,
                              void* d_out, int out_size, void* d_ws, size_t ws_size,
                              hipStream_t stream) {
    const float* x  = (const float*)d_in[0];
    const int*   ei = (const int*)d_in[1];
    const float* W1 = (const float*)d_in[2];
    const float* b1 = (const float*)d_in[3];
    const float* W2 = (const float*)d_in[4];
    const float* b2 = (const float*)d_in[5];
    float* out = (float*)d_out;

    const int* row = ei;            // sources
    const int* col = ei + N_EDGES;  // targets

    // workspace layout (20.8 MB total; h2 aliases h1 — h1 dead before layer2)
    char* ws = (char*)d_ws;
    float* dis    = (float*)(ws);                     // 400000 B
    int*   offs   = (int*)(ws + 400000);              // 400016 B (N+1)
    int*   deg    = (int*)(ws + 800016);              // 400000 B
    int*   cursor = (int*)(ws + 1200016);             // 400000 B
    int*   csr    = (int*)(ws + 1600016);             // 12800000 B
    u16*   h1     = (u16*)(ws + 14400016);            // 3200000 B (N*16 bf16)
    u16*   h2     = (u16*)(ws + 14400016);            // alias: 2000000 B (N*10 bf16)
    u16*   agg1   = (u16*)(ws + 17600016);            // 3200000 B
    float* agg2   = out;                              // d_out as scratch, finalized in place

    const int B = 256;
    int gN  = (N_NODES + B - 1) / B;
    int gE  = (N_EDGES + B - 1) / B;
    int gN16 = (int)(((long long)N_NODES * 16 + B - 1) / B);

    k_zero   <<<gN, B, 0, stream>>>(deg, cursor);
    k_count  <<<gE, B, 0, stream>>>(col, deg);
    k_scan   <<<1, 1024, 0, stream>>>(deg, offs, dis);
    k_gemm1  <<<gN, B, 0, stream>>>(x, W1, h1);
    k_bucket <<<gE, B, 0, stream>>>(row, col, offs, cursor, csr);
    k_gather1<<<gN16, B, 0, stream>>>(offs, csr, dis, h1, agg1);
    k_layer2 <<<gN, B, 0, stream>>>(agg1, b1, W2, h2);
    k_gather2<<<gN16, B, 0, stream>>>(offs, csr, dis, h2, agg2);
    k_final  <<<gN, B, 0, stream>>>(agg2, b2);
}

// Round 4
// 530.489 us; speedup vs baseline: 3.6960x; 1.4275x over previous
//
#include <hip/hip_runtime.h>
#include <math.h>

#define N_NODES 100000
#define N_EDGES 3200000
#define F_IN 128
#define HID 16
#define C_OUT 10
#define NB 391  // ceil(N_NODES/256)

typedef unsigned short u16;
typedef unsigned int u32;

__device__ __forceinline__ float bf2f(u16 u) {
    return __uint_as_float(((u32)u) << 16);
}
__device__ __forceinline__ u16 f2bf(float f) {
    u32 x = __float_as_uint(f);
    u32 r = (x + 0x7fffu + ((x >> 16) & 1u)) >> 16;  // round-nearest-even
    return (u16)r;
}

// ---------------- zero counters ----------------
__global__ void k_zero(int* __restrict__ deg, int* __restrict__ cursor) {
    int i = blockIdx.x * blockDim.x + threadIdx.x;
    if (i < N_NODES) { deg[i] = 0; cursor[i] = 0; }
}

// ---------------- in-degree count (int atomics) ----------------
__global__ void k_count(const int* __restrict__ col, int* __restrict__ deg) {
    int e = blockIdx.x * blockDim.x + threadIdx.x;
    if (e < N_EDGES) atomicAdd(&deg[col[e]], 1);
}

// ---------------- scan phase 1: per-block sums of deg ----------------
__global__ void k_bsum(const int* __restrict__ deg, int* __restrict__ bsum) {
    __shared__ int sm[256];
    int i = blockIdx.x * 256 + threadIdx.x;
    sm[threadIdx.x] = (i < N_NODES) ? deg[i] : 0;
    __syncthreads();
    for (int off = 128; off > 0; off >>= 1) {
        if (threadIdx.x < off) sm[threadIdx.x] += sm[threadIdx.x + off];
        __syncthreads();
    }
    if (threadIdx.x == 0) bsum[blockIdx.x] = sm[0];
}

// ---------------- scan phase 2: 1-block scan of NB=391 partials ----------------
__global__ void k_bscan(const int* __restrict__ bsum, int* __restrict__ bpre,
                        int* __restrict__ offs) {
    const int T = 512;
    __shared__ int part[T];
    int t = threadIdx.x;
    part[t] = (t < NB) ? bsum[t] : 0;
    __syncthreads();
    for (int off = 1; off < T; off <<= 1) {
        int v = part[t];
        int u = (t >= off) ? part[t - off] : 0;
        __syncthreads();
        part[t] = v + u;
        __syncthreads();
    }
    if (t < NB) bpre[t] = (t > 0) ? part[t - 1] : 0;
    if (t == T - 1) offs[N_NODES] = part[T - 1];  // = E
}

// ---------------- scan phase 3: per-block exclusive scan -> offs; dis ----------------
__global__ void k_offs(const int* __restrict__ deg, const int* __restrict__ bpre,
                       int* __restrict__ offs, float* __restrict__ dis) {
    __shared__ int sm[256];
    int i = blockIdx.x * 256 + threadIdx.x;
    int t = threadIdx.x;
    int d = (i < N_NODES) ? deg[i] : 0;
    sm[t] = d;
    __syncthreads();
    for (int off = 1; off < 256; off <<= 1) {
        int v = sm[t];
        int u = (t >= off) ? sm[t - off] : 0;
        __syncthreads();
        sm[t] = v + u;
        __syncthreads();
    }
    if (i < N_NODES) {
        int excl = sm[t] - d;  // exclusive prefix within block
        offs[i] = bpre[blockIdx.x] + excl;
        dis[i] = rsqrtf(1.0f + (float)d);
    }
}

// ---------------- bucket edges by target ----------------
__global__ void k_bucket(const int* __restrict__ row, const int* __restrict__ col,
                         const int* __restrict__ offs, int* __restrict__ cursor,
                         int* __restrict__ csr_src) {
    int e = blockIdx.x * blockDim.x + threadIdx.x;
    if (e >= N_EDGES) return;
    int c = col[e];
    int p = atomicAdd(&cursor[c], 1);
    csr_src[offs[c] + p] = row[e];
}

// ---------------- layer 1 GEMM: h1s = (x @ W1) * dis[node]  (bf16) ----------------
__global__ void k_gemm1(const float* __restrict__ x, const float* __restrict__ W1,
                        const float* __restrict__ dis, u16* __restrict__ h1s) {
    __shared__ float Ws[F_IN * HID];  // 8 KB
    for (int t = threadIdx.x; t < F_IN * HID; t += blockDim.x) Ws[t] = W1[t];
    __syncthreads();

    int node = blockIdx.x * blockDim.x + threadIdx.x;
    if (node >= N_NODES) return;

    float acc[HID];
#pragma unroll
    for (int j = 0; j < HID; j++) acc[j] = 0.f;

    const float4* xr = (const float4*)(x + (size_t)node * F_IN);
#pragma unroll 2
    for (int k4 = 0; k4 < F_IN / 4; k4++) {
        float4 v = xr[k4];
        float xv[4] = {v.x, v.y, v.z, v.w};
#pragma unroll
        for (int kk = 0; kk < 4; kk++) {
            const float4* wr = (const float4*)(Ws + (k4 * 4 + kk) * HID);
            float4 w0 = wr[0], w1 = wr[1], w2 = wr[2], w3 = wr[3];
            float xs = xv[kk];
            acc[0]  += xs * w0.x; acc[1]  += xs * w0.y; acc[2]  += xs * w0.z; acc[3]  += xs * w0.w;
            acc[4]  += xs * w1.x; acc[5]  += xs * w1.y; acc[6]  += xs * w1.z; acc[7]  += xs * w1.w;
            acc[8]  += xs * w2.x; acc[9]  += xs * w2.y; acc[10] += xs * w2.z; acc[11] += xs * w2.w;
            acc[12] += xs * w3.x; acc[13] += xs * w3.y; acc[14] += xs * w3.z; acc[15] += xs * w3.w;
        }
    }

    float d = dis[node];
    u32 p[8];
#pragma unroll
    for (int i = 0; i < 8; i++)
        p[i] = (u32)f2bf(acc[2 * i] * d) | ((u32)f2bf(acc[2 * i + 1] * d) << 16);
    u32* dst = (u32*)(h1s + (size_t)node * HID);
#pragma unroll
    for (int i = 0; i < 8; i++) dst[i] = p[i];
}

// ---------------- gather layer 1: agg1[c] = (h1s[c] + sum_s h1s[s]) * dis[c]  (bf16) ----------------
// 8 lanes/node, one u32 (2 features) per lane; each edge's row = one 32B segment.
__global__ void k_gather1(const int* __restrict__ offs, const int* __restrict__ csr_src,
                          const float* __restrict__ dis, const u16* __restrict__ h1s,
                          u16* __restrict__ agg1) {
    long long t = (long long)blockIdx.x * blockDim.x + threadIdx.x;
    if (t >= (long long)N_NODES * 8) return;
    int node = (int)(t >> 3);
    int f2 = (int)(t & 7);
    const u32* base = (const u32*)h1s;
    u32 v = base[(size_t)node * 8 + f2];  // self loop (already * dis[node])
    float a0 = bf2f((u16)(v & 0xffff));
    float a1 = bf2f((u16)(v >> 16));
    int s0 = offs[node], s1 = offs[node + 1];
    for (int j = s0; j < s1; j++) {
        int s = csr_src[j];  // broadcast across the node's 8 lanes
        u32 w = base[(size_t)s * 8 + f2];
        a0 += bf2f((u16)(w & 0xffff));
        a1 += bf2f((u16)(w >> 16));
    }
    float dc = dis[node];
    ((u32*)agg1)[(size_t)node * 8 + f2] =
        (u32)f2bf(a0 * dc) | ((u32)f2bf(a1 * dc) << 16);
}

// ---------------- layer 2: h = relu(agg1+b1); h2s = (h @ W2) * dis  (bf16, padded to 16) ----------------
__global__ void k_layer2(const u16* __restrict__ agg1, const float* __restrict__ b1,
                         const float* __restrict__ W2, const float* __restrict__ dis,
                         u16* __restrict__ h2s) {
    __shared__ float Ws[HID * C_OUT];
    __shared__ float b1s[HID];
    if (threadIdx.x < HID * C_OUT) Ws[threadIdx.x] = W2[threadIdx.x];
    if (threadIdx.x < HID) b1s[threadIdx.x] = b1[threadIdx.x];
    __syncthreads();

    int node = blockIdx.x * blockDim.x + threadIdx.x;
    if (node >= N_NODES) return;

    const uint4* ar = (const uint4*)(agg1 + (size_t)node * HID);
    uint4 q0 = ar[0], q1 = ar[1];
    u32 qs[8] = {q0.x, q0.y, q0.z, q0.w, q1.x, q1.y, q1.z, q1.w};

    float acc[C_OUT];
#pragma unroll
    for (int k = 0; k < C_OUT; k++) acc[k] = 0.f;

#pragma unroll
    for (int i = 0; i < 8; i++) {
        u32 q = qs[i];
        float v0 = bf2f((u16)(q & 0xffff));
        float v1 = bf2f((u16)(q >> 16));
        int j0 = 2 * i, j1 = 2 * i + 1;
        float h0 = fmaxf(v0 + b1s[j0], 0.f);
        float h1v = fmaxf(v1 + b1s[j1], 0.f);
#pragma unroll
        for (int k = 0; k < C_OUT; k++) acc[k] += h0 * Ws[j0 * C_OUT + k] + h1v * Ws[j1 * C_OUT + k];
    }

    float d = dis[node];
    u32 p[8];
#pragma unroll
    for (int i = 0; i < 5; i++)
        p[i] = (u32)f2bf(acc[2 * i] * d) | ((u32)f2bf(acc[2 * i + 1] * d) << 16);
    p[5] = 0; p[6] = 0; p[7] = 0;  // pad features 10..15 with zeros
    u32* dst = (u32*)(h2s + (size_t)node * HID);
#pragma unroll
    for (int i = 0; i < 8; i++) dst[i] = p[i];
}

// ---------------- gather layer 2: agg2 -> d_out (fp32, stride C_OUT) ----------------
__global__ void k_gather2(const int* __restrict__ offs, const int* __restrict__ csr_src,
                          const float* __restrict__ dis, const u16* __restrict__ h2s,
                          float* __restrict__ agg2) {
    long long t = (long long)blockIdx.x * blockDim.x + threadIdx.x;
    if (t >= (long long)N_NODES * 8) return;
    int node = (int)(t >> 3);
    int f2 = (int)(t & 7);
    const u32* base = (const u32*)h2s;
    u32 v = base[(size_t)node * 8 + f2];
    float a0 = bf2f((u16)(v & 0xffff));
    float a1 = bf2f((u16)(v >> 16));
    int s0 = offs[node], s1 = offs[node + 1];
    for (int j = s0; j < s1; j++) {
        int s = csr_src[j];
        u32 w = base[(size_t)s * 8 + f2];
        a0 += bf2f((u16)(w & 0xffff));
        a1 += bf2f((u16)(w >> 16));
    }
    if (f2 < 5) {  // features 2*f2, 2*f2+1 < 10
        float dc = dis[node];
        float2 o = make_float2(a0 * dc, a1 * dc);
        *(float2*)(agg2 + (size_t)node * C_OUT + 2 * f2) = o;  // 8B-aligned
    }
}

// ---------------- final: out = log_softmax(agg2 + b2), in place on d_out ----------------
__global__ void k_final(float* __restrict__ agg2, const float* __restrict__ b2) {
    __shared__ float b2s[C_OUT];
    if (threadIdx.x < C_OUT) b2s[threadIdx.x] = b2[threadIdx.x];
    __syncthreads();

    int i = blockIdx.x * blockDim.x + threadIdx.x;
    if (i >= N_NODES) return;

    float* ar = agg2 + (size_t)i * C_OUT;
    float v[C_OUT];
    float m = -1e30f;
#pragma unroll
    for (int k = 0; k < C_OUT; k++) {
        v[k] = ar[k] + b2s[k];
        m = fmaxf(m, v[k]);
    }
    float s = 0.f;
#pragma unroll
    for (int k = 0; k < C_OUT; k++) s += expf(v[k] - m);
    float ls = logf(s) + m;
#pragma unroll
    for (int k = 0; k < C_OUT; k++) ar[k] = v[k] - ls;
}

// ---------------- launch ----------------
extern "C" void kernel_launch(void* const* d_in, const int* in_sizes, int n_in,
                              void* d_out, int out_size, void* d_ws, size_t ws_size,
                              hipStream_t stream) {
    const float* x  = (const float*)d_in[0];
    const int*   ei = (const int*)d_in[1];
    const float* W1 = (const float*)d_in[2];
    const float* b1 = (const float*)d_in[3];
    const float* W2 = (const float*)d_in[4];
    const float* b2 = (const float*)d_in[5];
    float* out = (float*)d_out;

    const int* row = ei;            // sources
    const int* col = ei + N_EDGES;  // targets

    // workspace layout (~20.8 MB; h2s aliases h1s — h1s dead after gather1)
    char* ws = (char*)d_ws;
    float* dis    = (float*)(ws);                     // 400000 B
    int*   offs   = (int*)(ws + 400000);              // 400016 B (N+1)
    int*   deg    = (int*)(ws + 800016);              // 400000 B
    int*   cursor = (int*)(ws + 1200016);             // 400000 B
    int*   bsum   = (int*)(ws + 1600016);             // 1568 B
    int*   bpre   = (int*)(ws + 1601584);             // 1568 B
    int*   csr    = (int*)(ws + 1603152);             // 12800000 B
    u16*   h1s    = (u16*)(ws + 14403152);            // 3200000 B (N*16 bf16)
    u16*   h2s    = (u16*)(ws + 14403152);            // alias (padded to 16)
    u16*   agg1   = (u16*)(ws + 17603152);            // 3200000 B
    float* agg2   = out;                              // d_out, finalized in place

    const int B = 256;
    int gN  = (N_NODES + B - 1) / B;   // 391
    int gE  = (N_EDGES + B - 1) / B;
    int gN8 = (int)(((long long)N_NODES * 8 + B - 1) / B);

    k_zero   <<<gN, B, 0, stream>>>(deg, cursor);
    k_count  <<<gE, B, 0, stream>>>(col, deg);
    k_bsum   <<<NB, B, 0, stream>>>(deg, bsum);
    k_bscan  <<<1, 512, 0, stream>>>(bsum, bpre, offs);
    k_offs   <<<NB, B, 0, stream>>>(deg, bpre, offs, dis);
    k_gemm1  <<<gN, B, 0, stream>>>(x, W1, dis, h1s);
    k_bucket <<<gE, B, 0, stream>>>(row, col, offs, cursor, csr);
    k_gather1<<<gN8, B, 0, stream>>>(offs, csr, dis, h1s, agg1);
    k_layer2 <<<gN, B, 0, stream>>>(agg1, b1, W2, dis, h2s);
    k_gather2<<<gN8, B, 0, stream>>>(offs, csr, dis, h2s, agg2);
    k_final  <<<gN, B, 0, stream>>>(agg2, b2);
}